// Round 8
// baseline (83.497 us; speedup 1.0000x reference)
//
#include <hip/hip_runtime.h>

typedef __attribute__((ext_vector_type(4))) float f32x4;
typedef __attribute__((ext_vector_type(8))) short bf16x8;

constexpr int Bsz = 4096, Asz = 32, Isz = 256, Osz = 256;
constexpr int BM = 32, NKT = 8;
constexpr int NBLK = Asz * (Bsz / BM);   // 4096

// packed f32x2 -> bf16x2 (RNE); no builtin on gfx950
__device__ inline unsigned cvtpk(float lo, float hi) {
    unsigned r;
    asm("v_cvt_pk_bf16_f32 %0, %1, %2" : "=v"(r) : "v"(lo), "v"(hi));
    return r;
}

// async global->LDS DMA, 16B/lane; dest = wave-uniform base + lane*16 (linear)
__device__ inline void gl_lds16(const void* g, void* l) {
    __builtin_amdgcn_global_load_lds((const __attribute__((address_space(1))) void*)g,
                                     (__attribute__((address_space(3))) void*)l, 16, 0, 0);
}

// ---------------------------------------------------------------------------
// Pre-pack w [A,O,I] f32 -> bf16 fragment-linear: wf[((a*8+kt)*16+nf)*64+lane]
// = the 8 bf16 consumed by lane `lane` of B-fragment (a,kt,nf).
// o = nf*16 + (lane&15), i = kt*32 + (lane>>4)*8 .. +8
// ---------------------------------------------------------------------------
__global__ __launch_bounds__(256) void pack_w(const float* __restrict__ w,
                                              unsigned short* __restrict__ wf) {
    const int gid  = blockIdx.x * 256 + threadIdx.x;
    const int lane = gid & 63, nf = (gid >> 6) & 15, kt = (gid >> 10) & 7, a = gid >> 13;
    const int o  = nf * 16 + (lane & 15);
    const int i0 = kt * 32 + (lane >> 4) * 8;
    const float* s = w + (size_t)(a * Osz + o) * Isz + i0;
    f32x4 lo = *(const f32x4*)s, hi = *(const f32x4*)(s + 4);
    union { bf16x8 v; unsigned u[4]; } r;
    r.u[0] = cvtpk(lo[0], lo[1]); r.u[1] = cvtpk(lo[2], lo[3]);
    r.u[2] = cvtpk(hi[0], hi[1]); r.u[3] = cvtpk(hi[2], hi[3]);
    *(bf16x8*)(wf + (size_t)gid * 8) = r.v;
}

#define BLOAD(dst, kt)                                                         \
    _Pragma("unroll")                                                          \
    for (int n = 0; n < 4; ++n)                                                \
        dst[n] = *(const bf16x8*)(bp + (kt) * 8192 + n * 512);

#define ALOAD(dst, kt)                                                         \
    _Pragma("unroll")                                                          \
    for (int m = 0; m < 2; ++m) {                                              \
        const int ad = m * 16384 + abase + (kt) * 128;                         \
        f32x4 lo = *(const f32x4*)&sA[ad];                                     \
        f32x4 hi = *(const f32x4*)&sA[ad ^ 16];                                \
        union { bf16x8 v; unsigned u[4]; } r;                                  \
        r.u[0] = cvtpk(lo[0], lo[1]); r.u[1] = cvtpk(lo[2], lo[3]);            \
        r.u[2] = cvtpk(hi[0], hi[1]); r.u[3] = cvtpk(hi[2], hi[3]);            \
        dst[m] = r.v;                                                          \
    }

#define MFMAS(bsrc)                                                            \
    _Pragma("unroll")                                                          \
    for (int m = 0; m < 2; ++m)                                                \
        _Pragma("unroll")                                                      \
        for (int n = 0; n < 4; ++n)                                            \
            acc[m][n] = __builtin_amdgcn_mfma_f32_16x16x32_bf16(aF[m], bsrc[n], acc[m][n], 0, 0, 0);

// ---------------------------------------------------------------------------
// Main GEMM: BM=32 rows/block, full K staged up-front (32 KB LDS -> 4
// blocks/CU), ONE barrier. B loads register-double-buffered (static names)
// and PINNED one kt ahead with sched_barrier(0) so the scheduler cannot sink
// them to use-point: L2 latency hides under the previous kt's ds_read+MFMA.
// ---------------------------------------------------------------------------
__global__ __launch_bounds__(256, 4) void al_gemm(const float* __restrict__ x,
                                                  const unsigned short* __restrict__ wf,
                                                  const float* __restrict__ bias,
                                                  float* __restrict__ out)
{
    __shared__ char sA[32768];   // 32 rows x 64 chunks(16B), low-3 chunk-swizzled

    // XCD-contiguous bijective swizzle (4096 % 8 == 0): 512 ids/XCD = 4 a's.
    const int p  = blockIdx.x;
    const int l  = (p & 7) * (NBLK / 8) + (p >> 3);
    const int a  = l >> 7;
    const int b0 = (l & 127) * BM;

    const int t    = threadIdx.x;
    const int wid  = t >> 6;
    const int lane = t & 63;
    const int llo  = lane & 15, lhi = lane >> 4;
    const int nb   = wid * 64;

    // ---- stage whole 32x256 f32 tile: wave wid does rows wid*8..wid*8+7 ----
    // phys chunk-in-row = lane; global chunk cq = (lane&56) | ((lane&7)^j)
#pragma unroll
    for (int j = 0; j < 8; ++j) {
        const int row = wid * 8 + j;
        const int cq  = (lane & 56) | ((lane & 7) ^ j);
        const float* src = x + ((size_t)(b0 + row) * Asz + a) * Isz + cq * 4;
        gl_lds16(src, &sA[wid * 8192 + j * 1024]);
    }

    // B direct from L2-resident wf: wave's 4 frags per kt = 4 contiguous 1KB lines
    const unsigned short* bp = wf + (size_t)a * (Osz * Isz) + wid * 2048 + lane * 8;

    // bias folded into acc init (all 4 regs of a C-frag share col nb+n*16+llo)
    f32x4 acc[2][4];
#pragma unroll
    for (int n = 0; n < 4; ++n) {
        const float bv = bias[a * Osz + nb + n * 16 + llo];
#pragma unroll
        for (int m = 0; m < 2; ++m) acc[m][n] = (f32x4)(bv);
    }

    // compute-side LDS addr: row=m*16+llo, phys chunk = kt*8 + ((2*lhi)^(llo&7))
    const int abase = llo * 1024 + (((2 * lhi) ^ (llo & 7)) << 4);

    bf16x8 bA[4], bB[4];          // static double-buffered B registers
    BLOAD(bA, 0);                 // kt=0 B in flight before the barrier wait
    __builtin_amdgcn_sched_barrier(0);

    __syncthreads();              // drains A-DMAs, joins waves

    bf16x8 aF[2];
#pragma unroll
    for (int kt2 = 0; kt2 < 4; ++kt2) {
        // even kt = 2*kt2: prefetch odd, pin, compute with bA
        BLOAD(bB, 2 * kt2 + 1);
        __builtin_amdgcn_sched_barrier(0);
        ALOAD(aF, 2 * kt2);
        MFMAS(bA);
        // odd kt = 2*kt2+1: prefetch next even, pin, compute with bB
        if (kt2 < 3) { BLOAD(bA, 2 * kt2 + 2); }
        __builtin_amdgcn_sched_barrier(0);
        ALOAD(aF, 2 * kt2 + 1);
        MFMAS(bB);
    }

    // Epilogue: D[row = m*16 + lhi*4 + r][col = nb + n*16 + llo]
#pragma unroll
    for (int n = 0; n < 4; ++n) {
        const int col = nb + n * 16 + llo;
#pragma unroll
        for (int m = 0; m < 2; ++m) {
            const int row = b0 + m * 16 + lhi * 4;
            float* op = out + ((size_t)row * Asz + a) * Osz + col;
#pragma unroll
            for (int r = 0; r < 4; ++r)
                op[(size_t)r * Asz * Osz] = acc[m][n][r];
        }
    }
}

extern "C" void kernel_launch(void* const* d_in, const int* in_sizes, int n_in,
                              void* d_out, int out_size, void* d_ws, size_t ws_size,
                              hipStream_t stream) {
    const float* x    = (const float*)d_in[0];
    const float* w    = (const float*)d_in[1];
    const float* bias = (const float*)d_in[2];
    float* out        = (float*)d_out;
    unsigned short* wf = (unsigned short*)d_ws;   // 4 MB

    pack_w<<<dim3(Asz * NKT * 16 * 64 / 256), dim3(256), 0, stream>>>(w, wf);
    al_gemm<<<dim3(NBLK), dim3(256), 0, stream>>>(x, wf, bias, out);
}

// Round 9
// 76.664 us; speedup vs baseline: 1.0891x; 1.0891x over previous
//
#include <hip/hip_runtime.h>

typedef __attribute__((ext_vector_type(4))) float f32x4;
typedef __attribute__((ext_vector_type(8))) short bf16x8;

constexpr int Bsz = 4096, Asz = 32, Isz = 256, Osz = 256;
constexpr int BM = 64, BK = 32, NKT = 8;
constexpr int NBLK = Asz * (Bsz / BM);   // 2048

// packed f32x2 -> bf16x2 (RNE); no builtin on gfx950
__device__ inline unsigned cvtpk(float lo, float hi) {
    unsigned r;
    asm("v_cvt_pk_bf16_f32 %0, %1, %2" : "=v"(r) : "v"(lo), "v"(hi));
    return r;
}

// async global->LDS DMA, 16B/lane; dest = wave-uniform base + lane*16 (linear)
__device__ inline void gl_lds16(const void* g, void* l) {
    __builtin_amdgcn_global_load_lds((const __attribute__((address_space(1))) void*)g,
                                     (__attribute__((address_space(3))) void*)l, 16, 0, 0);
}

// ---------------------------------------------------------------------------
// Pre-pack w [A,O,I] f32 -> bf16 fragment-linear: wf[((a*8+kt)*16+nf)*64+lane]
// = the 8 bf16 consumed by lane `lane` of B-fragment (a,kt,nf).
// o = nf*16 + (lane&15), i = kt*32 + (lane>>4)*8 .. +8
// ---------------------------------------------------------------------------
__global__ __launch_bounds__(256) void pack_w(const float* __restrict__ w,
                                              unsigned short* __restrict__ wf) {
    const int gid  = blockIdx.x * 256 + threadIdx.x;
    const int lane = gid & 63, nf = (gid >> 6) & 15, kt = (gid >> 10) & 7, a = gid >> 13;
    const int o  = nf * 16 + (lane & 15);
    const int i0 = kt * 32 + (lane >> 4) * 8;
    const float* s = w + (size_t)(a * Osz + o) * Isz + i0;
    f32x4 lo = *(const f32x4*)s, hi = *(const f32x4*)(s + 4);
    union { bf16x8 v; unsigned u[4]; } r;
    r.u[0] = cvtpk(lo[0], lo[1]); r.u[1] = cvtpk(lo[2], lo[3]);
    r.u[2] = cvtpk(hi[0], hi[1]); r.u[3] = cvtpk(hi[2], hi[3]);
    *(bf16x8*)(wf + (size_t)gid * 8) = r.v;
}

// ---------------------------------------------------------------------------
// Main GEMM: BM=64, 512 threads (8 waves = 2 Mh x 4 Nq). ALL loads via
// global_load_lds (the only reliably-early-issuing load on hipcc):
//   A: ring-3 8KB kt-slices, staged 2 kt ahead (HBM cover), src XOR-swizzled.
//   B: ring-2 16KB kt-slices from fragment-linear wf (L2), staged 1 kt ahead.
// Per kt: counted s_waitcnt vmcnt(1) (NEVER drains the newest A-stage) +
// s_barrier; stages issue post-barrier into the just-freed slot (race-safe).
// Bias applied in epilogue so no stray VMEM disturbs the vmcnt counts.
// ---------------------------------------------------------------------------
__global__ __launch_bounds__(512, 4) void al_gemm(const float* __restrict__ x,
                                                  const unsigned short* __restrict__ wf,
                                                  const float* __restrict__ bias,
                                                  float* __restrict__ out)
{
    __shared__ char sA[3][8192];    // ring-3: 64 rows x 32 f32 per slot (swizzled)
    __shared__ char sB[2][16384];   // ring-2: 16 frags x 64 lanes x 16B per slot

    // XCD-contiguous bijective swizzle (2048 % 8 == 0): 256 ids/XCD = 4 a's.
    const int p  = blockIdx.x;
    const int l  = (p & 7) * (NBLK / 8) + (p >> 3);
    const int a  = l >> 6;
    const int b0 = (l & 63) * BM;

    const int t    = threadIdx.x;
    const int w    = t >> 6;          // wave 0..7
    const int lane = t & 63;
    const int llo  = lane & 15, lhi = lane >> 4;
    const int mh   = w >> 2;          // M-half  (rows mh*32..+31)
    const int nq   = w & 3;           // N-quarter (cols nq*64..+63)

    // --- A stage: wave w stages rows w*8..w*8+7 of the kt-slice (1 DMA/wave).
    // lane -> row j=lane>>3, phys chunk c=lane&7 holds global chunk c^j.
    const int   arow = w * 8 + (lane >> 3);
    const int   acg  = (lane & 7) ^ (lane >> 3);
    const float* asrc = x + ((size_t)(b0 + arow) * Asz + a) * Isz + acg * 4;
    char* const adst  = &sA[0][0] + w * 1024 + lane * 16;   // + slot*8192

    // --- B stage: wave w stages bytes [w*2KB, w*2KB+2KB) of the 16KB kt-slice.
    const char* bsrc = (const char*)wf + (size_t)a * 131072 + w * 2048 + lane * 16;
    char* const bdst = &sB[0][0] + w * 2048 + lane * 16;    // + slot*16384 + q*1024

#define STAGE_B(kt) { _Pragma("unroll")                                         \
    for (int q = 0; q < 2; ++q)                                                 \
        gl_lds16(bsrc + (kt) * 16384 + q * 1024, bdst + ((kt) & 1) * 16384 + q * 1024); }
#define STAGE_A(kt)                                                             \
    gl_lds16(asrc + (kt) * BK, adst + ((kt) % 3) * 8192);

    // compute-side A addr: row = mh*32 + m*16 + llo (row&7 == llo&7),
    // global chunk g=2*lhi(+1) at phys g^(llo&7):
    const int abase = (mh * 32 + llo) * 128 + (((2 * lhi) ^ (llo & 7)) << 4);
    // compute-side B addr: frag nq*4+n, lane's 16B:
    const int bbase = nq * 4096 + lane * 16;

    f32x4 acc[2][4];
#pragma unroll
    for (int m = 0; m < 2; ++m)
#pragma unroll
        for (int n = 0; n < 4; ++n) acc[m][n] = (f32x4)0.f;

    // ---- prologue: B(0), A(0), A(1) in flight (A(1) is the newest) ----
    STAGE_B(0); STAGE_A(0); STAGE_A(1);

#pragma unroll
    for (int kt = 0; kt < NKT; ++kt) {
        // need stage(kt) landed; leave the newest A-stage in flight (never drain)
        if (kt == NKT - 1) asm volatile("s_waitcnt vmcnt(0) lgkmcnt(0)" ::: "memory");
        else               asm volatile("s_waitcnt vmcnt(1) lgkmcnt(0)" ::: "memory");
        __builtin_amdgcn_s_barrier();          // all waves' stage(kt) parts landed
        if (kt < NKT - 1) STAGE_B(kt + 1);     // into slot freed by B(kt-1)
        if (kt < NKT - 2) STAGE_A(kt + 2);     // into slot freed by A(kt-1)

        const char* As = &sA[0][0] + (kt % 3) * 8192;
        const char* Bs = &sB[0][0] + (kt & 1) * 16384;
        bf16x8 aF[2], bF[4];
#pragma unroll
        for (int m = 0; m < 2; ++m) {
            f32x4 lo = *(const f32x4*)(As + abase + m * 2048);
            f32x4 hi = *(const f32x4*)(As + ((abase + m * 2048) ^ 16));
            union { bf16x8 v; unsigned u[4]; } r;
            r.u[0] = cvtpk(lo[0], lo[1]); r.u[1] = cvtpk(lo[2], lo[3]);
            r.u[2] = cvtpk(hi[0], hi[1]); r.u[3] = cvtpk(hi[2], hi[3]);
            aF[m] = r.v;
        }
#pragma unroll
        for (int n = 0; n < 4; ++n)
            bF[n] = *(const bf16x8*)(Bs + bbase + n * 1024);
#pragma unroll
        for (int m = 0; m < 2; ++m)
#pragma unroll
            for (int n = 0; n < 4; ++n)
                acc[m][n] = __builtin_amdgcn_mfma_f32_16x16x32_bf16(aF[m], bF[n], acc[m][n], 0, 0, 0);
    }
#undef STAGE_A
#undef STAGE_B

    // Epilogue: bias + store. D[row = mh*32 + m*16 + lhi*4 + r][col = nq*64+n*16+llo]
#pragma unroll
    for (int n = 0; n < 4; ++n) {
        const int col = nq * 64 + n * 16 + llo;
        const float bv = bias[a * Osz + col];
#pragma unroll
        for (int m = 0; m < 2; ++m) {
            const int row = b0 + mh * 32 + m * 16 + lhi * 4;
            float* op = out + ((size_t)row * Asz + a) * Osz + col;
#pragma unroll
            for (int r = 0; r < 4; ++r)
                op[(size_t)r * Asz * Osz] = acc[m][n][r] + bv;
        }
    }
}

extern "C" void kernel_launch(void* const* d_in, const int* in_sizes, int n_in,
                              void* d_out, int out_size, void* d_ws, size_t ws_size,
                              hipStream_t stream) {
    const float* x    = (const float*)d_in[0];
    const float* w    = (const float*)d_in[1];
    const float* bias = (const float*)d_in[2];
    float* out        = (float*)d_out;
    unsigned short* wf = (unsigned short*)d_ws;   // 4 MB

    pack_w<<<dim3(Asz * NKT * 16 * 64 / 256), dim3(256), 0, stream>>>(w, wf);
    al_gemm<<<dim3(NBLK), dim3(512), 0, stream>>>(x, wf, bias, out);
}

// Round 10
// 75.628 us; speedup vs baseline: 1.1040x; 1.0137x over previous
//
#include <hip/hip_runtime.h>

typedef __attribute__((ext_vector_type(4))) float f32x4;
typedef __attribute__((ext_vector_type(8))) short bf16x8;

constexpr int Bsz = 4096, Asz = 32, Isz = 256, Osz = 256;
constexpr int BM = 32, NKT = 8;
constexpr int NBLK = Asz * (Bsz / BM);   // 4096

// packed f32x2 -> bf16x2 (RNE); no builtin on gfx950
__device__ inline unsigned cvtpk(float lo, float hi) {
    unsigned r;
    asm("v_cvt_pk_bf16_f32 %0, %1, %2" : "=v"(r) : "v"(lo), "v"(hi));
    return r;
}

// async global->LDS DMA, 16B/lane; dest = wave-uniform base + lane*16 (linear)
__device__ inline void gl_lds16(const void* g, void* l) {
    __builtin_amdgcn_global_load_lds((const __attribute__((address_space(1))) void*)g,
                                     (__attribute__((address_space(3))) void*)l, 16, 0, 0);
}

// ---------------------------------------------------------------------------
// Pre-pack w [A,O,I] f32 -> bf16 fragment-linear: wf[((a*8+kt)*16+nf)*64+lane]
// = the 8 bf16 consumed by lane `lane` of B-fragment (a,kt,nf).
// o = nf*16 + (lane&15), i = kt*32 + (lane>>4)*8 .. +8
// ---------------------------------------------------------------------------
__global__ __launch_bounds__(256) void pack_w(const float* __restrict__ w,
                                              unsigned short* __restrict__ wf) {
    const int gid  = blockIdx.x * 256 + threadIdx.x;
    const int lane = gid & 63, nf = (gid >> 6) & 15, kt = (gid >> 10) & 7, a = gid >> 13;
    const int o  = nf * 16 + (lane & 15);
    const int i0 = kt * 32 + (lane >> 4) * 8;
    const float* s = w + (size_t)(a * Osz + o) * Isz + i0;
    f32x4 lo = *(const f32x4*)s, hi = *(const f32x4*)(s + 4);
    union { bf16x8 v; unsigned u[4]; } r;
    r.u[0] = cvtpk(lo[0], lo[1]); r.u[1] = cvtpk(lo[2], lo[3]);
    r.u[2] = cvtpk(hi[0], hi[1]); r.u[3] = cvtpk(hi[2], hi[3]);
    *(bf16x8*)(wf + (size_t)gid * 8) = r.v;
}

// ---------------------------------------------------------------------------
// Main GEMM: BM=32, 256 threads (4 waves, wave w = O-quarter w*64..+63).
// B: the wave's ENTIRE working set (8kt x 4 frags = 128 VGPR) loaded ONCE in
// the prologue from fragment-linear wf and pinned with asm materializers --
// the only way hipcc keeps global loads in registers. A: full-K in LDS
// (32 KB, kt-major, XOR chunk swizzle, linear DMA dests). K-loop: pure
// ds_read+cvt+MFMA -- NO VMEM, NO barriers, NO waitcnts. 2 blocks/CU so
// prologue fill / store drain of one block overlaps the other's compute.
// ---------------------------------------------------------------------------
__global__ __launch_bounds__(256, 2) void al_gemm(const float* __restrict__ x,
                                                  const unsigned short* __restrict__ wf,
                                                  const float* __restrict__ bias,
                                                  float* __restrict__ out)
{
    __shared__ char sA[32768];   // [kt][32 rows][8 chunks of 16B], chunk-swizzled

    // XCD-contiguous bijective swizzle (4096 % 8 == 0): 512 ids/XCD = 4 a's.
    const int p  = blockIdx.x;
    const int l  = (p & 7) * (NBLK / 8) + (p >> 3);
    const int a  = l >> 7;
    const int b0 = (l & 127) * BM;

    const int t    = threadIdx.x;
    const int w    = t >> 6;          // wave 0..3 = O-quarter
    const int lane = t & 63;
    const int llo  = lane & 15, lhi = lane >> 4;

    // ---- A staging: 8 DMAs/wave, one per kt-slice. Wave w stages rows
    // w*8..w*8+7. lane -> row w*8+(lane>>3), phys chunk lane&7 holds global
    // chunk (lane&7)^(lane>>3) of the kt-slice. Dest linear: w*1KB + lane*16.
    const int   arow = w * 8 + (lane >> 3);
    const int   acg  = (lane & 7) ^ (lane >> 3);
    const float* asrc = x + ((size_t)(b0 + arow) * Asz + a) * Isz + acg * 4;
    char* const adst  = &sA[0] + w * 1024 + lane * 16;
#pragma unroll
    for (int kt = 0; kt < NKT; ++kt)
        gl_lds16(asrc + kt * 32, adst + kt * 4096);

    // ---- B prologue load: 32 frags (4 contiguous 1KB lines per kt) ----
    const unsigned short* bp = wf + (size_t)a * 65536 + (w * 4) * 512 + lane * 8;
    bf16x8 breg[NKT][4];
#pragma unroll
    for (int kt = 0; kt < NKT; ++kt)
#pragma unroll
        for (int n = 0; n < 4; ++n)
            breg[kt][n] = *(const bf16x8*)(bp + kt * 8192 + n * 512);
    // Pin: a data dependency the scheduler cannot sink loads past. Forces all
    // 32 loads (and, FIFO-ordered before them, the 8 A-DMAs) to complete here.
#pragma unroll
    for (int kt = 0; kt < NKT; ++kt)
#pragma unroll
        for (int n = 0; n < 4; ++n)
            asm volatile("" : "+v"(breg[kt][n]));

    asm volatile("s_waitcnt vmcnt(0)" ::: "memory");
    __builtin_amdgcn_sched_barrier(0);
    __builtin_amdgcn_s_barrier();     // the ONLY barrier: A-tile ready

    f32x4 acc[2][4];
#pragma unroll
    for (int m = 0; m < 2; ++m)
#pragma unroll
        for (int n = 0; n < 4; ++n) acc[m][n] = (f32x4)0.f;

    // compute-side A addr: row = m*16+llo -> kt*4096 + m*2048 + llo*128 +
    // ((2*lhi)^(llo&7))*16 ; hi chunk = ^16.
    const int abase = llo * 128 + (((2 * lhi) ^ (llo & 7)) << 4);

#pragma unroll
    for (int kt = 0; kt < NKT; ++kt) {
        bf16x8 aF[2];
#pragma unroll
        for (int m = 0; m < 2; ++m) {
            const int ad = kt * 4096 + m * 2048 + abase;
            f32x4 lo = *(const f32x4*)&sA[ad];
            f32x4 hi = *(const f32x4*)&sA[ad ^ 16];
            union { bf16x8 v; unsigned u[4]; } r;
            r.u[0] = cvtpk(lo[0], lo[1]); r.u[1] = cvtpk(lo[2], lo[3]);
            r.u[2] = cvtpk(hi[0], hi[1]); r.u[3] = cvtpk(hi[2], hi[3]);
            aF[m] = r.v;
        }
#pragma unroll
        for (int m = 0; m < 2; ++m)
#pragma unroll
            for (int n = 0; n < 4; ++n)
                acc[m][n] = __builtin_amdgcn_mfma_f32_16x16x32_bf16(aF[m], breg[kt][n], acc[m][n], 0, 0, 0);
    }

    // Epilogue: bias + store. D[row = m*16 + lhi*4 + r][col = w*64 + n*16 + llo]
#pragma unroll
    for (int n = 0; n < 4; ++n) {
        const int col = w * 64 + n * 16 + llo;
        const float bv = bias[a * Osz + col];
#pragma unroll
        for (int m = 0; m < 2; ++m) {
            const int row = b0 + m * 16 + lhi * 4;
            float* op = out + ((size_t)row * Asz + a) * Osz + col;
#pragma unroll
            for (int r = 0; r < 4; ++r)
                op[(size_t)r * Asz * Osz] = acc[m][n][r] + bv;
        }
    }
}

extern "C" void kernel_launch(void* const* d_in, const int* in_sizes, int n_in,
                              void* d_out, int out_size, void* d_ws, size_t ws_size,
                              hipStream_t stream) {
    const float* x    = (const float*)d_in[0];
    const float* w    = (const float*)d_in[1];
    const float* bias = (const float*)d_in[2];
    float* out        = (float*)d_out;
    unsigned short* wf = (unsigned short*)d_ws;   // 4 MB

    pack_w<<<dim3(Asz * NKT * 16 * 64 / 256), dim3(256), 0, stream>>>(w, wf);
    al_gemm<<<dim3(NBLK), dim3(256), 0, stream>>>(x, wf, bias, out);
}

// Round 14
// 70.718 us; speedup vs baseline: 1.1807x; 1.0694x over previous
//
#include <hip/hip_runtime.h>

typedef __attribute__((ext_vector_type(4))) float f32x4;
typedef __attribute__((ext_vector_type(4))) unsigned int u32x4;
typedef __attribute__((ext_vector_type(8))) short bf16x8;

constexpr int Bsz = 4096, Asz = 32, Isz = 256, Osz = 256;
constexpr int NT = 32;                 // 16-row tiles per block (512 rows)

// packed f32x2 -> bf16x2 (RNE); no builtin on gfx950
__device__ inline unsigned cvtpk(float lo, float hi) {
    unsigned r;
    asm("v_cvt_pk_bf16_f32 %0, %1, %2" : "=v"(r) : "v"(lo), "v"(hi));
    return r;
}

// async global->LDS DMA: dest = wave-uniform base (HW adds lane*16)
__device__ inline void gl_lds16(const void* g, void* l) {
    __builtin_amdgcn_global_load_lds((const __attribute__((address_space(1))) void*)g,
                                     (__attribute__((address_space(3))) void*)l, 16, 0, 0);
}

// ---------------------------------------------------------------------------
// Pre-pack w [A,O,I] f32 -> bf16 fragment-linear: wf[((a*8+kt)*16+nf)*64+lane]
// = the 8 bf16 consumed by lane `lane` of B-fragment (a,kt,nf).
// o = nf*16 + (lane&15), i = kt*32 + (lane>>4)*8 .. +8
// ---------------------------------------------------------------------------
__global__ __launch_bounds__(256) void pack_w(const float* __restrict__ w,
                                              unsigned short* __restrict__ wf) {
    const int gid  = blockIdx.x * 256 + threadIdx.x;
    const int lane = gid & 63, nf = (gid >> 6) & 15, kt = (gid >> 10) & 7, a = gid >> 13;
    const int o  = nf * 16 + (lane & 15);
    const int i0 = kt * 32 + (lane >> 4) * 8;
    const float* s = w + (size_t)(a * Osz + o) * Isz + i0;
    f32x4 lo = *(const f32x4*)s, hi = *(const f32x4*)(s + 4);
    union { bf16x8 v; unsigned u[4]; } r;
    r.u[0] = cvtpk(lo[0], lo[1]); r.u[1] = cvtpk(lo[2], lo[3]);
    r.u[2] = cvtpk(hi[0], hi[1]); r.u[3] = cvtpk(hi[2], hi[3]);
    *(bf16x8*)(wf + (size_t)gid * 8) = r.v;
}

// ---------------------------------------------------------------------------
// Main GEMM: 256 blocks (1/CU exact), 512 threads = 8 waves, 160 KB LDS.
// sB = block's ENTIRE pre-packed wf[a] (128 KB) staged once via ds_write;
// B never touches VMEM again. 32 tiles x 16 rows: double-buffered A fills
// via global_load_lds (dests < 32 KB: sA declared FIRST), one counted
// vmcnt(8) + one raw s_barrier per tile, stores never drained in-loop.
// sched_barrier(0) after ISSUE pins DMA-before-stores so the vmcnt FIFO
// arithmetic is sound (the round-13 reorder hole).
// Wave w: cols w*32..w*32+31 (2 B-frags); all waves share the A-frag.
// ---------------------------------------------------------------------------
__global__ __launch_bounds__(512, 2) void al_gemm(const float* __restrict__ x,
                                                  const unsigned short* __restrict__ wf,
                                                  const float* __restrict__ bias,
                                                  float* __restrict__ out)
{
    __shared__ char sA[2][16384];   // FIRST: DMA dests at offsets < 32 KB
    __shared__ char sB[131072];     // staged via ds_write (any offset safe)

    // 256 blocks: xcd p&7 hosts a in {4k..4k+3}; rowgroup p>>5 -> 512 rows.
    const int p  = blockIdx.x;
    const int a  = (p & 7) * 4 + ((p >> 3) & 3);
    const int b0 = (p >> 5) * 512;

    const int t    = threadIdx.x;
    const int w    = t >> 6;          // wave 0..7
    const int lane = t & 63;
    const int llo  = lane & 15, lhi = lane >> 4;

    // ---- A fill: wave w fills local rows 2w,2w+1 (1 KB row = 1 DMA each).
    // Phys chunk L holds logical chunk (L&56)|((L&7)^(row&7)) (XOR swizzle on
    // the per-lane SOURCE; LDS dest linear, rule #21).
    const int r0 = 2 * w, r1 = 2 * w + 1;
    const float* asrc0 = x + ((size_t)(b0 + r0) * Asz + a) * Isz
                           + ((lane & 56) | ((lane & 7) ^ (r0 & 7))) * 4;
    const float* asrc1 = x + ((size_t)(b0 + r1) * Asz + a) * Isz
                           + ((lane & 56) | ((lane & 7) ^ (r1 & 7))) * 4;

#define ISSUE(tn) {                                                            \
    const size_t o_ = (size_t)(tn) * (16 * Asz * Isz);                         \
    char* d_ = &sA[(tn) & 1][0];                                               \
    gl_lds16(asrc0 + o_, d_ + r0 * 1024);                                      \
    gl_lds16(asrc1 + o_, d_ + r1 * 1024); }

    ISSUE(0);
    __builtin_amdgcn_sched_barrier(0);

    // ---- stage sB once: regs -> ds_write_b128 (2 x 8 rounds of 8 KB) ----
    {
        const char* gsrc = (const char*)wf + (size_t)a * 131072 + t * 16;
        u32x4 v[8];
#pragma unroll
        for (int i = 0; i < 8; ++i) v[i] = *(const u32x4*)(gsrc + i * 8192);
#pragma unroll
        for (int i = 0; i < 8; ++i) *(u32x4*)&sB[i * 8192 + t * 16] = v[i];
#pragma unroll
        for (int i = 0; i < 8; ++i) v[i] = *(const u32x4*)(gsrc + 65536 + i * 8192);
#pragma unroll
        for (int i = 0; i < 8; ++i) *(u32x4*)&sB[65536 + i * 8192 + t * 16] = v[i];
    }

    const float bv0 = bias[a * Osz + w * 32 + llo];
    const float bv1 = bias[a * Osz + w * 32 + 16 + llo];

    __syncthreads();   // one-time full drain: fill(0) landed, sB visible

    // compute-side A addr: row llo (1 KB stride), phys chunk kt*8 + ((2lhi)^(llo&7))
    const int abase = llo * 1024 + (((2 * lhi) ^ (llo & 7)) << 4);

    for (int tn = 0; tn < NT; ++tn) {
        if (tn < NT - 1) ISSUE(tn + 1);
        __builtin_amdgcn_sched_barrier(0);   // pin DMAs before compute+stores

        const char* As = &sA[tn & 1][0];
        f32x4 acc0 = (f32x4)(bv0), acc1 = (f32x4)(bv1);
#pragma unroll
        for (int kt = 0; kt < 8; ++kt) {
            const int ad = abase + kt * 128;
            f32x4 lo = *(const f32x4*)(As + ad);
            f32x4 hi = *(const f32x4*)(As + (ad ^ 16));
            union { bf16x8 v; unsigned u[4]; } r;
            r.u[0] = cvtpk(lo[0], lo[1]); r.u[1] = cvtpk(lo[2], lo[3]);
            r.u[2] = cvtpk(hi[0], hi[1]); r.u[3] = cvtpk(hi[2], hi[3]);
            const bf16x8 aF = r.v;
            const bf16x8 bF0 = *(const bf16x8*)&sB[(kt * 16 + 2 * w) * 1024 + lane * 16];
            const bf16x8 bF1 = *(const bf16x8*)&sB[(kt * 16 + 2 * w + 1) * 1024 + lane * 16];
            acc0 = __builtin_amdgcn_mfma_f32_16x16x32_bf16(aF, bF0, acc0, 0, 0, 0);
            acc1 = __builtin_amdgcn_mfma_f32_16x16x32_bf16(aF, bF1, acc1, 0, 0, 0);
        }

        // stores: D[row = lhi*4 + r2][col = w*32 + nf*16 + llo]
        const int trow = b0 + tn * 16 + lhi * 4;
        float* op = out + ((size_t)trow * Asz + a) * Osz + w * 32 + llo;
#pragma unroll
        for (int r2 = 0; r2 < 4; ++r2) {
            op[(size_t)r2 * Asz * Osz]      = acc0[r2];
            op[(size_t)r2 * Asz * Osz + 16] = acc1[r2];
        }

        if (tn < NT - 1) {
            __builtin_amdgcn_sched_barrier(0);
            // outstanding: stores(tn-1):8 + fill(tn+1):2 + stores(tn):8
            // vmcnt(8) completes the 10 oldest -> fill landed, stores fly on
            asm volatile("s_waitcnt vmcnt(8)" ::: "memory");
            __builtin_amdgcn_sched_barrier(0);
            __builtin_amdgcn_s_barrier();    // raw: no implicit drain
        }
    }
#undef ISSUE
}

extern "C" void kernel_launch(void* const* d_in, const int* in_sizes, int n_in,
                              void* d_out, int out_size, void* d_ws, size_t ws_size,
                              hipStream_t stream) {
    const float* x    = (const float*)d_in[0];
    const float* w    = (const float*)d_in[1];
    const float* bias = (const float*)d_in[2];
    float* out        = (float*)d_out;
    unsigned short* wf = (unsigned short*)d_ws;   // 4 MB

    pack_w<<<dim3(Asz * 8 * 16 * 64 / 256), dim3(256), 0, stream>>>(w, wf);
    al_gemm<<<dim3(256), dim3(512), 0, stream>>>(x, wf, bias, out);
}

// Round 15
// 67.747 us; speedup vs baseline: 1.2325x; 1.0439x over previous
//
#include <hip/hip_runtime.h>

typedef __attribute__((ext_vector_type(4))) float f32x4;
typedef __attribute__((ext_vector_type(8))) short bf16x8;

constexpr int Bsz = 4096, Asz = 32, Isz = 256, Osz = 256;
constexpr int NT = 32;                 // 16-row tiles per block (512 rows)

// packed f32x2 -> bf16x2 (RNE); no builtin on gfx950
__device__ inline unsigned cvtpk(float lo, float hi) {
    unsigned r;
    asm("v_cvt_pk_bf16_f32 %0, %1, %2" : "=v"(r) : "v"(lo), "v"(hi));
    return r;
}

// async global->LDS DMA: dest = wave-uniform base (HW adds lane*16)
__device__ inline void gl_lds16(const void* g, void* l) {
    __builtin_amdgcn_global_load_lds((const __attribute__((address_space(1))) void*)g,
                                     (__attribute__((address_space(3))) void*)l, 16, 0, 0);
}

// ---------------------------------------------------------------------------
// Single fused kernel (pack_w folded into the prologue; d_ws unused).
// 256 blocks (1/CU exact), 512 threads = 8 waves, 160 KB LDS.
//   sA[2][16KB] declared FIRST (DMA dests stay < 32 KB — the r11 lesson).
//   sB[128KB]   = block's entire w[a] packed f32->bf16 fragment-linear in the
//                 prologue (w[a] is L2-resident: all 8 blocks sharing `a` sit
//                 on one XCD). B never touches VMEM in the main loop.
// 32 tiles x 16 rows: double-buffered A fills via global_load_lds, ONE
// counted vmcnt(8) + ONE raw s_barrier per tile, stores never drained.
// CRITICAL INVARIANT (r13 post-mortem): no compiler-generated VMEM may enter
// the counted window — bias kept in exactly 2 VGPRs, all else LDS/registers.
// ---------------------------------------------------------------------------
__global__ __launch_bounds__(512, 2) void al_gemm(const float* __restrict__ x,
                                                  const float* __restrict__ wsrc,
                                                  const float* __restrict__ bias,
                                                  float* __restrict__ out)
{
    __shared__ char sA[2][16384];   // FIRST: DMA dests at offsets < 32 KB
    __shared__ char sB[131072];     // packed B, written via ds_write (any offset)

    // 256 blocks: xcd p&7 hosts a in {4k..4k+3}; rowgroup p>>5 -> 512 rows.
    const int p  = blockIdx.x;
    const int a  = (p & 7) * 4 + ((p >> 3) & 3);
    const int b0 = (p >> 5) * 512;

    const int t    = threadIdx.x;
    const int w    = t >> 6;          // wave 0..7
    const int lane = t & 63;
    const int llo  = lane & 15, lhi = lane >> 4;

    // ---- A fill: wave w fills local rows 2w,2w+1 (1 KB row = 1 DMA each).
    // Phys chunk L holds logical chunk (L&56)|((L&7)^(row&7)) (XOR swizzle on
    // the per-lane SOURCE; LDS dest linear, rule #21).
    const int r0 = 2 * w, r1 = 2 * w + 1;
    const float* asrc0 = x + ((size_t)(b0 + r0) * Asz + a) * Isz
                           + ((lane & 56) | ((lane & 7) ^ (r0 & 7))) * 4;
    const float* asrc1 = x + ((size_t)(b0 + r1) * Asz + a) * Isz
                           + ((lane & 56) | ((lane & 7) ^ (r1 & 7))) * 4;

#define ISSUE(tn) {                                                            \
    const size_t o_ = (size_t)(tn) * (16 * Asz * Isz);                         \
    char* d_ = &sA[(tn) & 1][0];                                               \
    gl_lds16(asrc0 + o_, d_ + r0 * 1024);                                      \
    gl_lds16(asrc1 + o_, d_ + r1 * 1024); }

    ISSUE(0);                            // fly during the pack below
    __builtin_amdgcn_sched_barrier(0);

    // ---- pack w[a] f32 -> sB bf16, fragment-linear:
    // chunk idx = (kt*16+nf)*64+lane_ holds the 8 bf16 lane lane_ consumes for
    // B-frag (kt,nf): o = nf*16+(lane_&15), i = kt*32+(lane_>>4)*8 .. +8
    {
        const float* wa = wsrc + (size_t)a * (Osz * Isz);
#pragma unroll
        for (int i = 0; i < 16; ++i) {
            const int idx   = i * 512 + t;
            const int lane_ = idx & 63, nf = (idx >> 6) & 15, kt = idx >> 10;
            const float* s  = wa + (size_t)(nf * 16 + (lane_ & 15)) * Isz
                                 + kt * 32 + (lane_ >> 4) * 8;
            f32x4 lo = *(const f32x4*)s, hi = *(const f32x4*)(s + 4);
            union { bf16x8 v; unsigned u[4]; } r;
            r.u[0] = cvtpk(lo[0], lo[1]); r.u[1] = cvtpk(lo[2], lo[3]);
            r.u[2] = cvtpk(hi[0], hi[1]); r.u[3] = cvtpk(hi[2], hi[3]);
            *(bf16x8*)&sB[idx * 16] = r.v;
        }
    }

    // bias in exactly 2 VGPRs (more risks in-loop remat -> breaks vmcnt FIFO)
    const float bv0 = bias[a * Osz + w * 32 + llo];
    const float bv1 = bias[a * Osz + w * 32 + 16 + llo];

    __syncthreads();   // one-time full drain: fill(0) + pack loads; sB visible

    // compute-side A addr: row llo (1 KB stride), phys chunk kt*8 + ((2lhi)^(llo&7))
    const int abase = llo * 1024 + (((2 * lhi) ^ (llo & 7)) << 4);

    for (int tn = 0; tn < NT; ++tn) {
        if (tn < NT - 1) ISSUE(tn + 1);
        __builtin_amdgcn_sched_barrier(0);   // pin DMAs before compute+stores

        const char* As = &sA[tn & 1][0];
        f32x4 acc0 = (f32x4)(bv0), acc1 = (f32x4)(bv1);
#pragma unroll
        for (int kt = 0; kt < 8; ++kt) {
            const int ad = abase + kt * 128;
            f32x4 lo = *(const f32x4*)(As + ad);
            f32x4 hi = *(const f32x4*)(As + (ad ^ 16));
            union { bf16x8 v; unsigned u[4]; } r;
            r.u[0] = cvtpk(lo[0], lo[1]); r.u[1] = cvtpk(lo[2], lo[3]);
            r.u[2] = cvtpk(hi[0], hi[1]); r.u[3] = cvtpk(hi[2], hi[3]);
            const bf16x8 aF = r.v;
            const bf16x8 bF0 = *(const bf16x8*)&sB[(kt * 16 + 2 * w) * 1024 + lane * 16];
            const bf16x8 bF1 = *(const bf16x8*)&sB[(kt * 16 + 2 * w + 1) * 1024 + lane * 16];
            acc0 = __builtin_amdgcn_mfma_f32_16x16x32_bf16(aF, bF0, acc0, 0, 0, 0);
            acc1 = __builtin_amdgcn_mfma_f32_16x16x32_bf16(aF, bF1, acc1, 0, 0, 0);
        }

        // stores: D[row = lhi*4 + r2][col = w*32 + nf*16 + llo]
        const int trow = b0 + tn * 16 + lhi * 4;
        float* op = out + ((size_t)trow * Asz + a) * Osz + w * 32 + llo;
#pragma unroll
        for (int r2 = 0; r2 < 4; ++r2) {
            op[(size_t)r2 * Asz * Osz]      = acc0[r2];
            op[(size_t)r2 * Asz * Osz + 16] = acc1[r2];
        }

        if (tn < NT - 1) {
            __builtin_amdgcn_sched_barrier(0);
            // outstanding: stores(tn-1):8 + fill(tn+1):2 + stores(tn):8
            // vmcnt(8) completes the 10 oldest -> fill landed, stores fly on
            asm volatile("s_waitcnt vmcnt(8)" ::: "memory");
            __builtin_amdgcn_sched_barrier(0);
            __builtin_amdgcn_s_barrier();    // raw: no implicit drain
        }
    }
#undef ISSUE
}

extern "C" void kernel_launch(void* const* d_in, const int* in_sizes, int n_in,
                              void* d_out, int out_size, void* d_ws, size_t ws_size,
                              hipStream_t stream) {
    const float* x    = (const float*)d_in[0];
    const float* w    = (const float*)d_in[1];
    const float* bias = (const float*)d_in[2];
    float* out        = (float*)d_out;
    al_gemm<<<dim3(256), dim3(512), 0, stream>>>(x, w, bias, out);
}

// Round 19
// 64.692 us; speedup vs baseline: 1.2907x; 1.0472x over previous
//
#include <hip/hip_runtime.h>

typedef __attribute__((ext_vector_type(4))) float f32x4;
typedef __attribute__((ext_vector_type(8))) short bf16x8;

constexpr int Bsz = 4096, Asz = 32, Isz = 256, Osz = 256;
constexpr int NT = 32;                 // 16-row tiles per block (512 rows)

// packed f32x2 -> bf16x2 (RNE); no builtin on gfx950
__device__ inline unsigned cvtpk(float lo, float hi) {
    unsigned r;
    asm("v_cvt_pk_bf16_f32 %0, %1, %2" : "=v"(r) : "v"(lo), "v"(hi));
    return r;
}

// async global->LDS DMA: dest = wave-uniform base (HW adds lane*16)
__device__ inline void gl_lds16(const void* g, void* l) {
    __builtin_amdgcn_global_load_lds((const __attribute__((address_space(1))) void*)g,
                                     (__attribute__((address_space(3))) void*)l, 16, 0, 0);
}

// ---------------------------------------------------------------------------
// r19 = r15 (proven 67.7us PASS) + two zero-risk deltas:
//   (1) pack reads w[a] COALESCED (thread t reads 8 contiguous f32; bijective
//       slot->fragment remap) instead of 1KB-strided scatter.
//   (2) s_setprio(1) around the per-tile ds_read+MFMA cluster (T5).
// Structure: 256 blocks (1/CU), 512 threads = 8 waves, 160 KB LDS.
// sA[2][16KB] FIRST (DMA dests < 32 KB — r11). sB[128KB] = w[a] packed
// f32->bf16 fragment-linear in prologue. 32 tiles x 16 rows: double-buffered
// A fills via global_load_lds, counted vmcnt(8) + raw s_barrier per tile.
// INVARIANTS: bias in exactly 2 VGPRs (r13); NO B-register-hoist (r16-r18
// NaN'd 3x with it, mechanism undiagnosable at source level).
// ---------------------------------------------------------------------------
__global__ __launch_bounds__(512, 2) void al_gemm(const float* __restrict__ x,
                                                  const float* __restrict__ wsrc,
                                                  const float* __restrict__ bias,
                                                  float* __restrict__ out)
{
    __shared__ char sA[2][16384];   // FIRST: DMA dests at offsets < 32 KB
    __shared__ char sB[131072];     // packed B, written via ds_write (any offset)

    // 256 blocks: xcd p&7 hosts a in {4k..4k+3}; rowgroup p>>5 -> 512 rows.
    const int p  = blockIdx.x;
    const int a  = (p & 7) * 4 + ((p >> 3) & 3);
    const int b0 = (p >> 5) * 512;

    const int t    = threadIdx.x;
    const int w    = t >> 6;          // wave 0..7
    const int lane = t & 63;
    const int llo  = lane & 15, lhi = lane >> 4;

    // ---- A fill: wave w fills local rows 2w,2w+1 (1 KB row = 1 DMA each).
    // Phys chunk L holds logical chunk (L&56)|((L&7)^(row&7)) (XOR swizzle on
    // the per-lane SOURCE; LDS dest linear, rule #21).
    const int r0 = 2 * w, r1 = 2 * w + 1;
    const float* asrc0 = x + ((size_t)(b0 + r0) * Asz + a) * Isz
                           + ((lane & 56) | ((lane & 7) ^ (r0 & 7))) * 4;
    const float* asrc1 = x + ((size_t)(b0 + r1) * Asz + a) * Isz
                           + ((lane & 56) | ((lane & 7) ^ (r1 & 7))) * 4;

#define ISSUE(tn) {                                                            \
    const size_t o_ = (size_t)(tn) * (16 * Asz * Isz);                         \
    char* d_ = &sA[(tn) & 1][0];                                               \
    gl_lds16(asrc0 + o_, d_ + r0 * 1024);                                      \
    gl_lds16(asrc1 + o_, d_ + r1 * 1024); }

    ISSUE(0);                            // fly during the pack below
    __builtin_amdgcn_sched_barrier(0);

    // ---- pack w[a] f32 -> sB bf16, fragment-linear — COALESCED reads:
    // slot s = i*512+t covers the 8 CONTIGUOUS f32 at wa + s*8, which are
    // exactly one lane-slot of one fragment: o = s>>5, kt = (s>>2)&7,
    // nf = s>>9, lane_ = (o&15) | ((s&3)<<4). Bijective over 8192 slots.
    {
        const float* wa = wsrc + (size_t)a * (Osz * Isz);
#pragma unroll
        for (int i = 0; i < 16; ++i) {
            const int s     = i * 512 + t;
            const int o     = s >> 5;
            const int kt    = (s >> 2) & 7;
            const int nf    = s >> 9;
            const int lane_ = (o & 15) | ((s & 3) << 4);
            f32x4 lo = *(const f32x4*)(wa + (size_t)s * 8);
            f32x4 hi = *(const f32x4*)(wa + (size_t)s * 8 + 4);
            union { bf16x8 v; unsigned u[4]; } r;
            r.u[0] = cvtpk(lo[0], lo[1]); r.u[1] = cvtpk(lo[2], lo[3]);
            r.u[2] = cvtpk(hi[0], hi[1]); r.u[3] = cvtpk(hi[2], hi[3]);
            *(bf16x8*)&sB[(((kt * 16 + nf) * 64) + lane_) * 16] = r.v;
        }
    }

    // bias in exactly 2 VGPRs (more risks in-loop remat -> breaks vmcnt FIFO)
    const float bv0 = bias[a * Osz + w * 32 + llo];
    const float bv1 = bias[a * Osz + w * 32 + 16 + llo];

    __syncthreads();   // one-time full drain: fill(0) + pack stores visible

    // compute-side A addr: row llo (1 KB stride), phys chunk kt*8 + ((2lhi)^(llo&7))
    const int abase = llo * 1024 + (((2 * lhi) ^ (llo & 7)) << 4);

    for (int tn = 0; tn < NT; ++tn) {
        if (tn < NT - 1) ISSUE(tn + 1);
        __builtin_amdgcn_sched_barrier(0);   // pin DMAs before compute+stores

        const char* As = &sA[tn & 1][0];
        f32x4 acc0 = (f32x4)(bv0), acc1 = (f32x4)(bv1);
        __builtin_amdgcn_s_setprio(1);       // T5: favor MFMA-phase waves
#pragma unroll
        for (int kt = 0; kt < 8; ++kt) {
            const int ad = abase + kt * 128;
            f32x4 lo = *(const f32x4*)(As + ad);
            f32x4 hi = *(const f32x4*)(As + (ad ^ 16));
            union { bf16x8 v; unsigned u[4]; } r;
            r.u[0] = cvtpk(lo[0], lo[1]); r.u[1] = cvtpk(lo[2], lo[3]);
            r.u[2] = cvtpk(hi[0], hi[1]); r.u[3] = cvtpk(hi[2], hi[3]);
            const bf16x8 aF = r.v;
            const bf16x8 bF0 = *(const bf16x8*)&sB[(kt * 16 + 2 * w) * 1024 + lane * 16];
            const bf16x8 bF1 = *(const bf16x8*)&sB[(kt * 16 + 2 * w + 1) * 1024 + lane * 16];
            acc0 = __builtin_amdgcn_mfma_f32_16x16x32_bf16(aF, bF0, acc0, 0, 0, 0);
            acc1 = __builtin_amdgcn_mfma_f32_16x16x32_bf16(aF, bF1, acc1, 0, 0, 0);
        }
        __builtin_amdgcn_s_setprio(0);

        // stores: D[row = lhi*4 + r2][col = w*32 + {0,16} + llo]
        const int trow = b0 + tn * 16 + lhi * 4;
        float* op = out + ((size_t)trow * Asz + a) * Osz + w * 32 + llo;
#pragma unroll
        for (int r2 = 0; r2 < 4; ++r2) {
            op[(size_t)r2 * Asz * Osz]      = acc0[r2];
            op[(size_t)r2 * Asz * Osz + 16] = acc1[r2];
        }

        if (tn < NT - 1) {
            __builtin_amdgcn_sched_barrier(0);
            // outstanding: stores(tn-1):8 + fill(tn+1):2 + stores(tn):8
            // vmcnt(8) completes the 10 oldest -> fill landed, stores fly on
            asm volatile("s_waitcnt vmcnt(8)" ::: "memory");
            __builtin_amdgcn_sched_barrier(0);
            __builtin_amdgcn_s_barrier();    // raw: no implicit drain
        }
    }
#undef ISSUE
}

extern "C" void kernel_launch(void* const* d_in, const int* in_sizes, int n_in,
                              void* d_out, int out_size, void* d_ws, size_t ws_size,
                              hipStream_t stream) {
    const float* x    = (const float*)d_in[0];
    const float* w    = (const float*)d_in[1];
    const float* bias = (const float*)d_in[2];
    float* out        = (float*)d_out;
    al_gemm<<<dim3(256), dim3(512), 0, stream>>>(x, w, bias, out);
}

// Round 20
// 60.178 us; speedup vs baseline: 1.3875x; 1.0750x over previous
//
#include <hip/hip_runtime.h>

typedef __attribute__((ext_vector_type(4))) float f32x4;
typedef __attribute__((ext_vector_type(2))) unsigned u32x2;
typedef __attribute__((ext_vector_type(8))) short bf16x8;

constexpr int Bsz = 4096, Asz = 32, Isz = 256, Osz = 256;
constexpr int NT = 32;                 // 16-row tiles per block (512 rows)

// packed f32x2 -> bf16x2 (RNE); no builtin on gfx950
__device__ inline unsigned cvtpk(float lo, float hi) {
    unsigned r;
    asm("v_cvt_pk_bf16_f32 %0, %1, %2" : "=v"(r) : "v"(lo), "v"(hi));
    return r;
}

// ---------------------------------------------------------------------------
// r20 = r19 structure, but A is staged as BF16 via registers (not f32 via
// DMA): per kt the A-frag is ONE ds_read_b128 (not two + cvt) — per-tile LDS
// drops 256->192 reads and all cvt_pk leave the inner loop. This also removes
// every NaN-prone lever: NO global_load_lds, NO counted vmcnt (plain
// __syncthreads per tile; fill loads are compiler-tracked), NO B-reg-hoist.
// 256 blocks (1/CU), 512 threads = 8 waves, 144 KB LDS.
// sA[2][8KB] bf16, chunk-XOR swizzle (16B chunk c at c^row): reads 2-way.
// sB[128KB] = w[a] packed bf16 fragment-linear (r19 coalesced pack).
// Per tile: issue fill(tn+1) loads (pinned) -> compute (24 ds_read + 16 MFMA,
// setprio) -> stores (never waited) -> cvt+ds_write fill -> __syncthreads.
// ---------------------------------------------------------------------------
__global__ __launch_bounds__(512, 2) void al_gemm(const float* __restrict__ x,
                                                  const float* __restrict__ wsrc,
                                                  const float* __restrict__ bias,
                                                  float* __restrict__ out)
{
    __shared__ char sA[2][8192];    // 16 rows x 512B (bf16), XOR-swizzled
    __shared__ char sB[131072];     // packed B, fragment-linear

    // 256 blocks: xcd p&7 hosts a in {4k..4k+3}; rowgroup p>>5 -> 512 rows.
    const int p  = blockIdx.x;
    const int a  = (p & 7) * 4 + ((p >> 3) & 3);
    const int b0 = (p >> 5) * 512;

    const int t    = threadIdx.x;
    const int w    = t >> 6;          // wave 0..7
    const int lane = t & 63;
    const int llo  = lane & 15, lhi = lane >> 4;

    // ---- A fill (reg-staged): wave w covers tile-local rows 2w, 2w+1.
    // Lane holds f32 k = lane*4..+3 of its row -> 2 cvt_pk -> 8B bf16 ->
    // ds_write_b64 at swizzled chunk ((lane>>1)^row)*16 + (lane&1)*8.
    const int lr0 = 2 * w, lr1 = 2 * w + 1;
    const float* fs0 = x + ((size_t)(b0 + lr0) * Asz + a) * Isz + lane * 4;
    const float* fs1 = x + ((size_t)(b0 + lr1) * Asz + a) * Isz + lane * 4;
    const int wa0 = lr0 * 512 + (((lane >> 1) ^ lr0) << 4) + (lane & 1) * 8;
    const int wa1 = lr1 * 512 + (((lane >> 1) ^ lr1) << 4) + (lane & 1) * 8;

    f32x4 L0, L1;                     // in-flight fill registers (8 VGPR)
    L0 = *(const f32x4*)fs0;          // L(0)
    L1 = *(const f32x4*)fs1;
    asm volatile("" : "+v"(L0), "+v"(L1));   // pin: keep issued here

    // ---- pack w[a] f32 -> sB bf16, fragment-linear — COALESCED (r19):
    // slot s = i*512+t -> 8 contiguous f32 at wa+s*8 = lane-slot of frag:
    // o = s>>5, kt = (s>>2)&7, nf = s>>9, lane_ = (o&15) | ((s&3)<<4).
    {
        const float* wa = wsrc + (size_t)a * (Osz * Isz);
#pragma unroll
        for (int i = 0; i < 16; ++i) {
            const int s     = i * 512 + t;
            const int o     = s >> 5;
            const int kt    = (s >> 2) & 7;
            const int nf    = s >> 9;
            const int lane_ = (o & 15) | ((s & 3) << 4);
            f32x4 lo = *(const f32x4*)(wa + (size_t)s * 8);
            f32x4 hi = *(const f32x4*)(wa + (size_t)s * 8 + 4);
            union { bf16x8 v; unsigned u[4]; } r;
            r.u[0] = cvtpk(lo[0], lo[1]); r.u[1] = cvtpk(lo[2], lo[3]);
            r.u[2] = cvtpk(hi[0], hi[1]); r.u[3] = cvtpk(hi[2], hi[3]);
            *(bf16x8*)&sB[(((kt * 16 + nf) * 64) + lane_) * 16] = r.v;
        }
    }

    const float bv0 = bias[a * Osz + w * 32 + llo];
    const float bv1 = bias[a * Osz + w * 32 + 16 + llo];

    // write L(0) into sA[0]
    *(u32x2*)&sA[0][wa0] = (u32x2){cvtpk(L0[0], L0[1]), cvtpk(L0[2], L0[3])};
    *(u32x2*)&sA[0][wa1] = (u32x2){cvtpk(L1[0], L1[1]), cvtpk(L1[2], L1[3])};

    __syncthreads();   // sA[0] + sB visible

    for (int tn = 0; tn < NT; ++tn) {
        if (tn < NT - 1) {             // issue fill(tn+1); latency hides under compute
            const size_t o_ = (size_t)(tn + 1) * (16 * Asz * Isz);
            L0 = *(const f32x4*)(fs0 + o_);
            L1 = *(const f32x4*)(fs1 + o_);
            asm volatile("" : "+v"(L0), "+v"(L1));
        }

        const char* As = &sA[tn & 1][0];
        f32x4 acc0 = (f32x4)(bv0), acc1 = (f32x4)(bv1);
        __builtin_amdgcn_s_setprio(1);
#pragma unroll
        for (int kt = 0; kt < 8; ++kt) {
            // A: one b128 at row llo, swizzled chunk (kt*4+lhi)^llo
            const bf16x8 aF = *(const bf16x8*)&As[llo * 512 + ((((kt * 4) + lhi) ^ llo) << 4)];
            const bf16x8 bF0 = *(const bf16x8*)&sB[(kt * 16 + 2 * w) * 1024 + lane * 16];
            const bf16x8 bF1 = *(const bf16x8*)&sB[(kt * 16 + 2 * w + 1) * 1024 + lane * 16];
            acc0 = __builtin_amdgcn_mfma_f32_16x16x32_bf16(aF, bF0, acc0, 0, 0, 0);
            acc1 = __builtin_amdgcn_mfma_f32_16x16x32_bf16(aF, bF1, acc1, 0, 0, 0);
        }
        __builtin_amdgcn_s_setprio(0);

        // stores: D[row = lhi*4 + r2][col = w*32 + {0,16} + llo]; never waited
        const int trow = b0 + tn * 16 + lhi * 4;
        float* op = out + ((size_t)trow * Asz + a) * Osz + w * 32 + llo;
#pragma unroll
        for (int r2 = 0; r2 < 4; ++r2) {
            op[(size_t)r2 * Asz * Osz]      = acc0[r2];
            op[(size_t)r2 * Asz * Osz + 16] = acc1[r2];
        }

        if (tn < NT - 1) {             // cvt + write fill into the other buffer
            char* Ad = &sA[(tn + 1) & 1][0];
            *(u32x2*)&Ad[wa0] = (u32x2){cvtpk(L0[0], L0[1]), cvtpk(L0[2], L0[3])};
            *(u32x2*)&Ad[wa1] = (u32x2){cvtpk(L1[0], L1[1]), cvtpk(L1[2], L1[3])};
        }

        __syncthreads();   // fill visible; all reads of old buffer done
    }
}

extern "C" void kernel_launch(void* const* d_in, const int* in_sizes, int n_in,
                              void* d_out, int out_size, void* d_ws, size_t ws_size,
                              hipStream_t stream) {
    const float* x    = (const float*)d_in[0];
    const float* w    = (const float*)d_in[1];
    const float* bias = (const float*)d_in[2];
    float* out        = (float*)d_out;
    al_gemm<<<dim3(256), dim3(512), 0, stream>>>(x, w, bias, out);
}

// Round 21
// 58.790 us; speedup vs baseline: 1.4203x; 1.0236x over previous
//
#include <hip/hip_runtime.h>

typedef __attribute__((ext_vector_type(4))) float f32x4;
typedef __attribute__((ext_vector_type(2))) unsigned u32x2;
typedef __attribute__((ext_vector_type(8))) short bf16x8;

constexpr int Bsz = 4096, Asz = 32, Isz = 256, Osz = 256;
constexpr int NI = 16;                 // iterations of 32-row super-tiles

// packed f32x2 -> bf16x2 (RNE); no builtin on gfx950
__device__ inline unsigned cvtpk(float lo, float hi) {
    unsigned r;
    asm("v_cvt_pk_bf16_f32 %0, %1, %2" : "=v"(r) : "v"(lo), "v"(hi));
    return r;
}

// ---------------------------------------------------------------------------
// r21 = r20 with 2 tiles (32 rows) per barrier period: per kt each wave reads
// 2 A-frags + 2 B-frags and does 4 MFMAs — B-reads amortize over both tiles,
// per-tile LDS reads drop 24->16, barrier count halves. LDS = exactly 160 KB
// (sA 2x16KB + sB 128KB). Same safe mechanisms as r20: reg-staged bf16 A
// (pinned loads, compiler-tracked), plain __syncthreads, no DMA/vmcnt/B-hoist.
// 256 blocks (1/CU), 512 threads = 8 waves.
// ---------------------------------------------------------------------------
__global__ __launch_bounds__(512, 2) void al_gemm(const float* __restrict__ x,
                                                  const float* __restrict__ wsrc,
                                                  const float* __restrict__ bias,
                                                  float* __restrict__ out)
{
    __shared__ char sA[2][16384];   // 32 rows x 512B (bf16), chunk-XOR swizzled
    __shared__ char sB[131072];     // packed B, fragment-linear

    // 256 blocks: xcd p&7 hosts a in {4k..4k+3}; rowgroup p>>5 -> 512 rows.
    const int p  = blockIdx.x;
    const int a  = (p & 7) * 4 + ((p >> 3) & 3);
    const int b0 = (p >> 5) * 512;

    const int t    = threadIdx.x;
    const int w    = t >> 6;          // wave 0..7
    const int lane = t & 63;
    const int llo  = lane & 15, lhi = lane >> 4;

    // ---- A fill (reg-staged): wave w covers super-tile-local rows 4w..4w+3.
    // Lane holds f32 k = lane*4..+3 of its row -> 2 cvt_pk -> ds_write_b64 at
    // swizzled chunk ((lane>>1)^row)*16 + (lane&1)*8.
    const float* fs[4];
    int wadr[4];
#pragma unroll
    for (int j = 0; j < 4; ++j) {
        const int lr = 4 * w + j;
        fs[j]   = x + ((size_t)(b0 + lr) * Asz + a) * Isz + lane * 4;
        wadr[j] = lr * 512 + (((lane >> 1) ^ lr) << 4) + (lane & 1) * 8;
    }

    f32x4 L[4];                       // in-flight fill registers (16 VGPR)
#pragma unroll
    for (int j = 0; j < 4; ++j) L[j] = *(const f32x4*)fs[j];
    asm volatile("" : "+v"(L[0]), "+v"(L[1]), "+v"(L[2]), "+v"(L[3]));

    // ---- pack w[a] f32 -> sB bf16, fragment-linear — COALESCED (r19):
    // slot s = i*512+t -> 8 contiguous f32 at wa+s*8 = lane-slot of frag:
    // o = s>>5, kt = (s>>2)&7, nf = s>>9, lane_ = (o&15) | ((s&3)<<4).
    {
        const float* wa = wsrc + (size_t)a * (Osz * Isz);
#pragma unroll
        for (int i = 0; i < 16; ++i) {
            const int s     = i * 512 + t;
            const int o     = s >> 5;
            const int kt    = (s >> 2) & 7;
            const int nf    = s >> 9;
            const int lane_ = (o & 15) | ((s & 3) << 4);
            f32x4 lo = *(const f32x4*)(wa + (size_t)s * 8);
            f32x4 hi = *(const f32x4*)(wa + (size_t)s * 8 + 4);
            union { bf16x8 v; unsigned u[4]; } r;
            r.u[0] = cvtpk(lo[0], lo[1]); r.u[1] = cvtpk(lo[2], lo[3]);
            r.u[2] = cvtpk(hi[0], hi[1]); r.u[3] = cvtpk(hi[2], hi[3]);
            *(bf16x8*)&sB[(((kt * 16 + nf) * 64) + lane_) * 16] = r.v;
        }
    }

    const float bv0 = bias[a * Osz + w * 32 + llo];
    const float bv1 = bias[a * Osz + w * 32 + 16 + llo];

    // write L(0) into sA[0]
#pragma unroll
    for (int j = 0; j < 4; ++j)
        *(u32x2*)&sA[0][wadr[j]] = (u32x2){cvtpk(L[j][0], L[j][1]), cvtpk(L[j][2], L[j][3])};

    __syncthreads();   // sA[0] + sB visible

    // compute-side A addrs: tile0 row = llo, tile1 row = llo+16;
    // chunk c = kt*4+lhi read at (c ^ row)*16.
    const int lr1 = llo + 16;

    for (int tn = 0; tn < NI; ++tn) {
        if (tn < NI - 1) {             // issue fill(tn+1); hides under compute
            const size_t o_ = (size_t)(tn + 1) * (32 * Asz * Isz);
#pragma unroll
            for (int j = 0; j < 4; ++j) L[j] = *(const f32x4*)(fs[j] + o_);
            asm volatile("" : "+v"(L[0]), "+v"(L[1]), "+v"(L[2]), "+v"(L[3]));
        }

        const char* As = &sA[tn & 1][0];
        f32x4 acc00 = (f32x4)(bv0), acc01 = (f32x4)(bv1);   // tile0
        f32x4 acc10 = (f32x4)(bv0), acc11 = (f32x4)(bv1);   // tile1
        __builtin_amdgcn_s_setprio(1);
#pragma unroll
        for (int kt = 0; kt < 8; ++kt) {
            const int c = kt * 4 + lhi;
            const bf16x8 aF0 = *(const bf16x8*)&As[llo * 512 + ((c ^ llo) << 4)];
            const bf16x8 aF1 = *(const bf16x8*)&As[lr1 * 512 + ((c ^ lr1) << 4)];
            const bf16x8 bF0 = *(const bf16x8*)&sB[(kt * 16 + 2 * w) * 1024 + lane * 16];
            const bf16x8 bF1 = *(const bf16x8*)&sB[(kt * 16 + 2 * w + 1) * 1024 + lane * 16];
            acc00 = __builtin_amdgcn_mfma_f32_16x16x32_bf16(aF0, bF0, acc00, 0, 0, 0);
            acc01 = __builtin_amdgcn_mfma_f32_16x16x32_bf16(aF0, bF1, acc01, 0, 0, 0);
            acc10 = __builtin_amdgcn_mfma_f32_16x16x32_bf16(aF1, bF0, acc10, 0, 0, 0);
            acc11 = __builtin_amdgcn_mfma_f32_16x16x32_bf16(aF1, bF1, acc11, 0, 0, 0);
        }
        __builtin_amdgcn_s_setprio(0);

        // stores: tile0 rows b0+tn*32+lhi*4+r2, tile1 +16
        const int trow = b0 + tn * 32 + lhi * 4;
        float* op0 = out + ((size_t)trow * Asz + a) * Osz + w * 32 + llo;
        float* op1 = op0 + (size_t)16 * Asz * Osz;
#pragma unroll
        for (int r2 = 0; r2 < 4; ++r2) {
            op0[(size_t)r2 * Asz * Osz]      = acc00[r2];
            op0[(size_t)r2 * Asz * Osz + 16] = acc01[r2];
            op1[(size_t)r2 * Asz * Osz]      = acc10[r2];
            op1[(size_t)r2 * Asz * Osz + 16] = acc11[r2];
        }

        if (tn < NI - 1) {             // cvt + write fill into the other buffer
            char* Ad = &sA[(tn + 1) & 1][0];
#pragma unroll
            for (int j = 0; j < 4; ++j)
                *(u32x2*)&Ad[wadr[j]] = (u32x2){cvtpk(L[j][0], L[j][1]), cvtpk(L[j][2], L[j][3])};
        }

        __syncthreads();   // fill visible; all reads of old buffer done
    }
}

extern "C" void kernel_launch(void* const* d_in, const int* in_sizes, int n_in,
                              void* d_out, int out_size, void* d_ws, size_t ws_size,
                              hipStream_t stream) {
    const float* x    = (const float*)d_in[0];
    const float* w    = (const float*)d_in[1];
    const float* bias = (const float*)d_in[2];
    float* out        = (float*)d_out;
    al_gemm<<<dim3(256), dim3(512), 0, stream>>>(x, w, bias, out);
}